// Round 1
// baseline (4052.903 us; speedup 1.0000x reference)
//
#include <hip/hip_runtime.h>
#include <cstddef>

// Problem constants (from reference): Bn=256, N=197, C=192, H=3, hd=64, E=1024, hid=768
// M = Bn*N = 50432 rows (= 788 * 64 exactly).
//
// ws layout (needs ~185 MB):
//   [0, 154927104)                : h1 (50432*768 f32)  -- also overlays qkv (50432*576 f32, dead before h1 written)
//   [154927104, +38731776)        : aggmsg (50432*192 f32)
//   [193658880, +1024)            : cnt (256 int)

// ---------------------------------------------------------------------------
// Generic 64x64-tile fp32 GEMM  C = f( LN?(A) @ W^T ), 256 threads, 4x4/thread
// MODE 0: qkv    (fused LN1, no bias)
// MODE 1: proj   (epilogue: /max(cnt,1), bias*(cnt>0), + x residual)
// MODE 2: fc1    (fused LN2, +bias, exact gelu)
// MODE 3: fc2    (K=768 via 4 k-chunks, +bias, + x2 residual; C may alias xres elementwise)
// ---------------------------------------------------------------------------
template<int MODE, int NK>
__global__ __launch_bounds__(256) void gemm_kernel(
    const float* __restrict__ A, const float* __restrict__ W,
    const float* __restrict__ bias, const float* __restrict__ lng,
    const float* __restrict__ lnb, const float* xres,
    const int* __restrict__ cntg, float* C, int N)
{
  __shared__ float As[64][193];   // +1 pad: broadcast/2-way reads, conflict-free
  __shared__ float Bs[64][193];
  __shared__ float red0[64][4];
  __shared__ float red1[64][4];
  __shared__ float mb[64], rb[64];

  const int tid = threadIdx.x;
  const int m0 = blockIdx.x * 64, n0 = blockIdx.y * 64;
  const int ty = tid >> 4, tx = tid & 15;
  const int K = NK * 192;

  float acc[4][4];
#pragma unroll
  for (int i = 0; i < 4; ++i)
#pragma unroll
    for (int j = 0; j < 4; ++j) acc[i][j] = 0.f;

  for (int kc = 0; kc < NK; ++kc) {
    __syncthreads();   // protect LDS from previous iteration's readers
    // cooperative load: 64 rows x 192 cols each for A and W tiles (coalesced)
    for (int i = 0; i < 48; ++i) {
      int idx = i * 256 + tid;
      int r = idx / 192, c = idx - r * 192;
      As[r][c] = A[(size_t)(m0 + r) * K + kc * 192 + c];
      Bs[r][c] = W[(size_t)(n0 + r) * K + kc * 192 + c];
    }
    __syncthreads();

    if constexpr (MODE == 0 || MODE == 2) {
      // fused LayerNorm over each A row (K == 192 == full feature dim)
      int lr = tid >> 2, lq = tid & 3;
      float s = 0.f, ss = 0.f;
      for (int i = 0; i < 48; ++i) {
        float v = As[lr][lq * 48 + i];
        s += v; ss += v * v;
      }
      red0[lr][lq] = s; red1[lr][lq] = ss;
      __syncthreads();
      if (tid < 64) {
        float su = red0[tid][0] + red0[tid][1] + red0[tid][2] + red0[tid][3];
        float sq = red1[tid][0] + red1[tid][1] + red1[tid][2] + red1[tid][3];
        float mean = su * (1.f / 192.f);
        float var = sq * (1.f / 192.f) - mean * mean;
        mb[tid] = mean;
        rb[tid] = rsqrtf(var + 1e-5f);
      }
      __syncthreads();
      for (int i = 0; i < 48; ++i) {
        int idx = i * 256 + tid;
        int r = idx / 192, c = idx - r * 192;
        As[r][c] = (As[r][c] - mb[r]) * rb[r] * lng[c] + lnb[c];
      }
      __syncthreads();
    }

    const int ra = ty * 4, rb2 = tx * 4;
    for (int k = 0; k < 192; ++k) {
      float a0 = As[ra + 0][k], a1 = As[ra + 1][k], a2 = As[ra + 2][k], a3 = As[ra + 3][k];
      float b0 = Bs[rb2 + 0][k], b1 = Bs[rb2 + 1][k], b2 = Bs[rb2 + 2][k], b3 = Bs[rb2 + 3][k];
      acc[0][0] += a0 * b0; acc[0][1] += a0 * b1; acc[0][2] += a0 * b2; acc[0][3] += a0 * b3;
      acc[1][0] += a1 * b0; acc[1][1] += a1 * b1; acc[1][2] += a1 * b2; acc[1][3] += a1 * b3;
      acc[2][0] += a2 * b0; acc[2][1] += a2 * b1; acc[2][2] += a2 * b2; acc[2][3] += a2 * b3;
      acc[3][0] += a3 * b0; acc[3][1] += a3 * b1; acc[3][2] += a3 * b2; acc[3][3] += a3 * b3;
    }
  }

  // epilogue + coalesced float4 stores
#pragma unroll
  for (int i = 0; i < 4; ++i) {
    int row = m0 + ty * 4 + i;
    float v[4];
#pragma unroll
    for (int j = 0; j < 4; ++j) {
      int col = n0 + tx * 4 + j;
      float x = acc[i][j];
      if constexpr (MODE == 1) {
        int bn = row / 197;
        int c = cntg[bn];
        if (c > 0) x = x / (float)c + bias[col];
        else       x = 0.f;                      // agg==0, bias not applied when cnt==0
        x += xres[(size_t)row * 192 + col];
      } else if constexpr (MODE == 2) {
        x += bias[col];
        x = 0.5f * x * (1.f + erff(x * 0.70710678118654752f));  // exact gelu
      } else if constexpr (MODE == 3) {
        x += bias[col] + xres[(size_t)row * N + col];
      }
      v[j] = x;
    }
    float4 o = make_float4(v[0], v[1], v[2], v[3]);
    *reinterpret_cast<float4*>(&C[(size_t)row * N + n0 + tx * 4]) = o;
  }
}

// ---------------------------------------------------------------------------
// Attention per (dst node b, head h).  q,v come from dst; k from src.
// v resident in LDS (197x64); k streamed in 64-row tiles per incident edge.
// One thread per query row; branchy online softmax; Σ_edges msg accumulated in
// registers and written once to aggmsg.  cnt written as a byproduct.
// ---------------------------------------------------------------------------
__global__ __launch_bounds__(256, 1) void attn_kernel(
    const float* __restrict__ qkv, const int* __restrict__ edge,
    float* __restrict__ aggmsg, int* __restrict__ cntg)
{
  const int b = blockIdx.x;  // dst node
  const int h = blockIdx.y;  // head
  __shared__ __align__(16) float vs[197 * 64];
  __shared__ __align__(16) float ks[64 * 64];
  __shared__ int slist[1024];
  __shared__ int scnt;

  const int tid = threadIdx.x;
  if (tid == 0) scnt = 0;
  __syncthreads();

  const int* esrc = edge;
  const int* edst = edge + 1024;
  for (int e = tid; e < 1024; e += 256) {
    if (edst[e] == b) {
      int p = atomicAdd(&scnt, 1);
      slist[p] = esrc[e];
    }
  }
  // load v (from dst b) for this head: 197 rows x 64
  for (int i = tid; i < 197 * 16; i += 256) {
    int m = i >> 4, c4 = i & 15;
    *(float4*)(vs + m * 64 + c4 * 4) =
        *(const float4*)(qkv + (size_t)(b * 197 + m) * 576 + 384 + h * 64 + c4 * 4);
  }
  __syncthreads();
  const int cnt = scnt;
  if (h == 0 && tid == 0) cntg[b] = cnt;

  const int r = tid;
  const bool act = r < 197;
  float q[64], msum[64];
  if (act) {
    const float4* qp = (const float4*)(qkv + (size_t)(b * 197 + r) * 576 + h * 64);
#pragma unroll
    for (int dq = 0; dq < 16; ++dq) {
      float4 t = qp[dq];
      q[dq * 4 + 0] = t.x; q[dq * 4 + 1] = t.y; q[dq * 4 + 2] = t.z; q[dq * 4 + 3] = t.w;
    }
  }
#pragma unroll
  for (int d = 0; d < 64; ++d) msum[d] = 0.f;

  for (int ei = 0; ei < cnt; ++ei) {
    const int s = slist[ei];
    float mrun = -1e30f, l = 0.f;
    float out[64];
#pragma unroll
    for (int d = 0; d < 64; ++d) out[d] = 0.f;

    for (int t0 = 0; t0 < 197; t0 += 64) {
      const int tl = min(64, 197 - t0);
      __syncthreads();
      for (int i = tid; i < tl * 16; i += 256) {
        int m = i >> 4, c4 = i & 15;
        *(float4*)(ks + m * 64 + c4 * 4) =
            *(const float4*)(qkv + (size_t)(s * 197 + t0 + m) * 576 + 192 + h * 64 + c4 * 4);
      }
      __syncthreads();
      if (act) {
        for (int mm = 0; mm < tl; ++mm) {
          const float4* kr4 = (const float4*)(ks + mm * 64);
          float d0 = 0.f, d1 = 0.f, d2 = 0.f, d3 = 0.f;
#pragma unroll
          for (int dq = 0; dq < 16; ++dq) {
            float4 kk = kr4[dq];
            d0 += q[dq * 4 + 0] * kk.x; d1 += q[dq * 4 + 1] * kk.y;
            d2 += q[dq * 4 + 2] * kk.z; d3 += q[dq * 4 + 3] * kk.w;
          }
          float sc = (d0 + d1 + d2 + d3) * 0.125f;  // * hd^-0.5
          const float4* vr4 = (const float4*)(vs + (t0 + mm) * 64);
          if (sc <= mrun) {
            float w = __expf(sc - mrun);
            l += w;
#pragma unroll
            for (int dq = 0; dq < 16; ++dq) {
              float4 vv = vr4[dq];
              out[dq * 4 + 0] += w * vv.x; out[dq * 4 + 1] += w * vv.y;
              out[dq * 4 + 2] += w * vv.z; out[dq * 4 + 3] += w * vv.w;
            }
          } else {
            float al = __expf(mrun - sc);   // first key: exp(-huge)=0
            l = l * al + 1.f;
#pragma unroll
            for (int dq = 0; dq < 16; ++dq) {
              float4 vv = vr4[dq];
              out[dq * 4 + 0] = out[dq * 4 + 0] * al + vv.x;
              out[dq * 4 + 1] = out[dq * 4 + 1] * al + vv.y;
              out[dq * 4 + 2] = out[dq * 4 + 2] * al + vv.z;
              out[dq * 4 + 3] = out[dq * 4 + 3] * al + vv.w;
            }
            mrun = sc;
          }
        }
      }
    }
    if (act) {
      float inv = 1.f / l;
#pragma unroll
      for (int d = 0; d < 64; ++d) msum[d] += out[d] * inv;
    }
  }

  if (act) {
    float4* op = (float4*)(aggmsg + (size_t)(b * 197 + r) * 192 + h * 64);
#pragma unroll
    for (int dq = 0; dq < 16; ++dq)
      op[dq] = make_float4(msum[dq * 4 + 0], msum[dq * 4 + 1], msum[dq * 4 + 2], msum[dq * 4 + 3]);
  }
}

// ---------------------------------------------------------------------------
extern "C" void kernel_launch(void* const* d_in, const int* in_sizes, int n_in,
                              void* d_out, int out_size, void* d_ws, size_t ws_size,
                              hipStream_t stream)
{
  const float* x      = (const float*)d_in[0];
  const int*   edge   = (const int*)d_in[1];
  const float* n1g    = (const float*)d_in[2];
  const float* n1b    = (const float*)d_in[3];
  const float* qkv_w  = (const float*)d_in[4];
  const float* proj_w = (const float*)d_in[5];
  const float* proj_b = (const float*)d_in[6];
  const float* n2g    = (const float*)d_in[7];
  const float* n2b    = (const float*)d_in[8];
  const float* fc1_w  = (const float*)d_in[9];
  const float* fc1_b  = (const float*)d_in[10];
  const float* fc2_w  = (const float*)d_in[11];
  const float* fc2_b  = (const float*)d_in[12];
  float* out = (float*)d_out;

  char* ws = (char*)d_ws;
  float* h1     = (float*)ws;                                    // 50432*768 f32
  float* qkv    = (float*)ws;                                    // 50432*576 f32 (overlays h1; disjoint lifetime)
  float* aggmsg = (float*)(ws + 154927104);                      // 50432*192 f32
  int*   cntg   = (int*)  (ws + 154927104 + 38731776);           // 256 int

  dim3 blk(256);
  // 1) qkv = LN1(x) @ qkv_w^T
  gemm_kernel<0, 1><<<dim3(788, 9), blk, 0, stream>>>(x, qkv_w, nullptr, n1g, n1b, nullptr, nullptr, qkv, 576);
  // 2) per-(dst,head) edge attention -> aggmsg (= Σ_edges msg), cnt
  attn_kernel<<<dim3(256, 3), blk, 0, stream>>>(qkv, edge, aggmsg, cntg);
  // 3) x2 = x + proj(aggmsg)/max(cnt,1) + proj_b*(cnt>0)   -> d_out
  gemm_kernel<1, 1><<<dim3(788, 3), blk, 0, stream>>>(aggmsg, proj_w, proj_b, nullptr, nullptr, x, cntg, out, 192);
  // 4) h1 = gelu(LN2(x2) @ fc1_w^T + fc1_b)
  gemm_kernel<2, 1><<<dim3(788, 12), blk, 0, stream>>>(out, fc1_w, fc1_b, n2g, n2b, nullptr, nullptr, h1, 768);
  // 5) out = x2 + h1 @ fc2_w^T + fc2_b   (in-place on d_out, per-element RAW within thread)
  gemm_kernel<3, 4><<<dim3(788, 3), blk, 0, stream>>>(h1, fc2_w, fc2_b, nullptr, nullptr, out, nullptr, out, 192);
}

// Round 2
// 1262.818 us; speedup vs baseline: 3.2094x; 3.2094x over previous
//
#include <hip/hip_runtime.h>
#include <hip/hip_bf16.h>
#include <cstddef>

// Bn=256, N=197, C=192, H=3, hd=64, E=1024, hid=768, M = Bn*N = 50432 = 394*128
//
// ws layout (bytes), total ~175.2 MB (round-1 run proved >=193.6 MB available):
//   [0,          77463552)  : msgbuf bf16 [1024][197][192]  -- later overlaid by h1 bf16 [50432][768] (same size)
//   [77463552,  135561216)  : qkv bf16 [50432][576]
//   [135561216, 154927104)  : xn bf16 [50432][192]   (reused as x2n after proj)
//   [154927104, 174292992)  : agg bf16 [50432][192]
//   [174292992, +221184)    : qkv_w bf16
//   [...]                   : proj_w, fc1_w, fc2_w bf16
//   [175177728, +1024)      : cnt int32[256]

typedef __attribute__((ext_vector_type(8))) short bf8_t;
typedef __attribute__((ext_vector_type(4))) float f4_t;

__device__ __forceinline__ float bf2f(unsigned short u) {
  union { unsigned int i; float f; } x; x.i = ((unsigned int)u) << 16; return x.f;
}
__device__ __forceinline__ unsigned short f2bf(float f) {
  unsigned int u = __builtin_bit_cast(unsigned int, f);
  u = (u + 0x7FFFu + ((u >> 16) & 1u)) >> 16;
  return (unsigned short)u;
}

// ---------------------------------------------------------------------------
// fp32 -> bf16 elementwise (weights)
// ---------------------------------------------------------------------------
__global__ __launch_bounds__(256) void f2bf_kernel(const float* __restrict__ src,
                                                   unsigned short* __restrict__ dst, int n) {
  int i = blockIdx.x * 256 + threadIdx.x;
  if (i < n) dst[i] = f2bf(src[i]);
}

// ---------------------------------------------------------------------------
// LayerNorm(fp32 in) -> bf16 out.  One wave per row (C=192, 3 elems/lane).
// ---------------------------------------------------------------------------
__global__ __launch_bounds__(256) void ln_bf16_kernel(const float* __restrict__ X,
    const float* __restrict__ g, const float* __restrict__ b,
    unsigned short* __restrict__ Y) {
  int row = blockIdx.x * 4 + (threadIdx.x >> 6);
  int lane = threadIdx.x & 63;
  const float* xr = X + (size_t)row * 192;
  float v0 = xr[lane], v1 = xr[lane + 64], v2 = xr[lane + 128];
  float s = v0 + v1 + v2, ss = v0 * v0 + v1 * v1 + v2 * v2;
#pragma unroll
  for (int o = 32; o > 0; o >>= 1) { s += __shfl_xor(s, o, 64); ss += __shfl_xor(ss, o, 64); }
  float mean = s * (1.f / 192.f);
  float var = ss * (1.f / 192.f) - mean * mean;
  float r = rsqrtf(var + 1e-5f);
  unsigned short* yr = Y + (size_t)row * 192;
  yr[lane]       = f2bf((v0 - mean) * r * g[lane]       + b[lane]);
  yr[lane + 64]  = f2bf((v1 - mean) * r * g[lane + 64]  + b[lane + 64]);
  yr[lane + 128] = f2bf((v2 - mean) * r * g[lane + 128] + b[lane + 128]);
}

// ---------------------------------------------------------------------------
// bf16 MFMA GEMM: C = f( A @ W^T ), A [M x K] bf16, W [N x K] bf16, K = NK*192.
// Tile 128x64, 256 threads = 4 waves; wave w computes rows [32w,32w+32) as two
// 16-row m-tiles x four 16-col n-tiles of 16x16x32 MFMA.
// MODE 0: qkv   -> bf16 out
// MODE 1: proj  -> fp32 out: acc/cnt + bias (cnt>0) + xres
// MODE 2: fc1   -> bf16 out: gelu(acc + bias)
// MODE 3: fc2   -> fp32 out: acc + bias + xres (in-place safe per-element)
// ---------------------------------------------------------------------------
template<int MODE, int NK>
__global__ __launch_bounds__(256) void gemm_bf16(
    const unsigned short* __restrict__ A, const unsigned short* __restrict__ W,
    const float* __restrict__ bias, const float* __restrict__ xres,
    const int* __restrict__ cntg, void* __restrict__ Cout, int ldc) {
  constexpr int LDA = 200;  // bf16 elems per LDS row: 400 B -> rows step 4 banks, 2-way max (free)
  __shared__ unsigned short As[128 * LDA];
  __shared__ unsigned short Ws[64 * LDA];
  const int tid = threadIdx.x;
  const int m0 = blockIdx.x * 128, n0 = blockIdx.y * 64;
  const int wave = tid >> 6, lane = tid & 63;
  const int mfrag = lane & 15, quad = lane >> 4;
  const int K = NK * 192;

  f4_t acc[2][4];
#pragma unroll
  for (int i = 0; i < 2; ++i)
#pragma unroll
    for (int j = 0; j < 4; ++j) acc[i][j] = (f4_t){0.f, 0.f, 0.f, 0.f};

  for (int kc = 0; kc < NK; ++kc) {
    __syncthreads();
    // A tile: 128 rows x 24 float4 (8 bf16 each)
#pragma unroll
    for (int it = 0; it < 12; ++it) {
      int idx = it * 256 + tid;
      int r = idx / 24, c = idx % 24;
      *(float4*)(As + r * LDA + c * 8) =
          *(const float4*)(A + (size_t)(m0 + r) * K + kc * 192 + c * 8);
    }
#pragma unroll
    for (int it = 0; it < 6; ++it) {
      int idx = it * 256 + tid;
      int r = idx / 24, c = idx % 24;
      *(float4*)(Ws + r * LDA + c * 8) =
          *(const float4*)(W + (size_t)(n0 + r) * K + kc * 192 + c * 8);
    }
    __syncthreads();
#pragma unroll
    for (int ks = 0; ks < 6; ++ks) {
      bf8_t a0 = *(const bf8_t*)(As + (wave * 32 + mfrag) * LDA + ks * 32 + quad * 8);
      bf8_t a1 = *(const bf8_t*)(As + (wave * 32 + 16 + mfrag) * LDA + ks * 32 + quad * 8);
#pragma unroll
      for (int nt = 0; nt < 4; ++nt) {
        bf8_t bf = *(const bf8_t*)(Ws + (nt * 16 + mfrag) * LDA + ks * 32 + quad * 8);
        acc[0][nt] = __builtin_amdgcn_mfma_f32_16x16x32_bf16(a0, bf, acc[0][nt], 0, 0, 0);
        acc[1][nt] = __builtin_amdgcn_mfma_f32_16x16x32_bf16(a1, bf, acc[1][nt], 0, 0, 0);
      }
    }
  }

  // epilogue: C/D layout col=lane&15, row=quad*4+reg  [m89-verified]
#pragma unroll
  for (int mt = 0; mt < 2; ++mt)
#pragma unroll
    for (int nt = 0; nt < 4; ++nt)
#pragma unroll
      for (int reg = 0; reg < 4; ++reg) {
        int row = m0 + wave * 32 + mt * 16 + quad * 4 + reg;
        int col = n0 + nt * 16 + mfrag;
        float v = acc[mt][nt][reg];
        if constexpr (MODE == 0) {
          ((unsigned short*)Cout)[(size_t)row * ldc + col] = f2bf(v);
        } else if constexpr (MODE == 1) {
          int c = cntg[row / 197];
          v = (c > 0) ? v / (float)c + bias[col] : 0.f;
          v += xres[(size_t)row * 192 + col];
          ((float*)Cout)[(size_t)row * ldc + col] = v;
        } else if constexpr (MODE == 2) {
          v += bias[col];
          v = 0.5f * v * (1.f + erff(v * 0.70710678118654752f));
          ((unsigned short*)Cout)[(size_t)row * ldc + col] = f2bf(v);
        } else {
          v += bias[col] + xres[(size_t)row * 192 + col];
          ((float*)Cout)[(size_t)row * ldc + col] = v;
        }
      }
}

// ---------------------------------------------------------------------------
// Attention phase A: one block per (edge e, head h).  q,v from dst; k from src.
// fp32 compute from bf16 qkv; per-edge msg -> msgbuf bf16 [e][197][192].
// ---------------------------------------------------------------------------
__global__ __launch_bounds__(256) void attnA_kernel(
    const unsigned short* __restrict__ qkv, const int* __restrict__ edge,
    unsigned short* __restrict__ msgbuf) {
  const int e = blockIdx.x, h = blockIdx.y;
  const int s = edge[e], b = edge[1024 + e];
  __shared__ float vs[197 * 64];
  __shared__ float ks[64 * 64];
  const int tid = threadIdx.x;

  // v rows (dst b): 197 x 64, bf16 -> fp32 LDS
  for (int i = tid; i < 197 * 8; i += 256) {
    int m = i >> 3, c8 = i & 7;
    float4 t = *(const float4*)(qkv + (size_t)(b * 197 + m) * 576 + 384 + h * 64 + c8 * 8);
    const unsigned short* u = (const unsigned short*)&t;
    float* d = vs + m * 64 + c8 * 8;
#pragma unroll
    for (int j = 0; j < 8; ++j) d[j] = bf2f(u[j]);
  }

  const int r = tid;
  const bool act = r < 197;
  float q[64], out[64];
  if (act) {
    const float4* qp = (const float4*)(qkv + (size_t)(b * 197 + r) * 576 + h * 64);
#pragma unroll
    for (int c8 = 0; c8 < 8; ++c8) {
      float4 t = qp[c8];
      const unsigned short* u = (const unsigned short*)&t;
#pragma unroll
      for (int j = 0; j < 8; ++j) q[c8 * 8 + j] = bf2f(u[j]);
    }
  }
  float mrun = -1e30f, l = 0.f;
#pragma unroll
  for (int d = 0; d < 64; ++d) out[d] = 0.f;

  for (int t0 = 0; t0 < 197; t0 += 64) {
    const int tl = min(64, 197 - t0);
    __syncthreads();
    for (int i = tid; i < tl * 8; i += 256) {
      int m = i >> 3, c8 = i & 7;
      float4 t = *(const float4*)(qkv + (size_t)(s * 197 + t0 + m) * 576 + 192 + h * 64 + c8 * 8);
      const unsigned short* u = (const unsigned short*)&t;
      float* d = ks + m * 64 + c8 * 8;
#pragma unroll
      for (int j = 0; j < 8; ++j) d[j] = bf2f(u[j]);
    }
    __syncthreads();
    if (act) {
      for (int mm = 0; mm < tl; ++mm) {
        const float* kr = ks + mm * 64;
        float d0 = 0.f, d1 = 0.f, d2 = 0.f, d3 = 0.f;
#pragma unroll
        for (int dq = 0; dq < 16; ++dq) {
          d0 += q[dq * 4 + 0] * kr[dq * 4 + 0];
          d1 += q[dq * 4 + 1] * kr[dq * 4 + 1];
          d2 += q[dq * 4 + 2] * kr[dq * 4 + 2];
          d3 += q[dq * 4 + 3] * kr[dq * 4 + 3];
        }
        float sc = (d0 + d1 + d2 + d3) * 0.125f;
        const float* vr = vs + (t0 + mm) * 64;
        if (sc <= mrun) {
          float w = __expf(sc - mrun);
          l += w;
#pragma unroll
          for (int d = 0; d < 64; ++d) out[d] += w * vr[d];
        } else {
          float al = __expf(mrun - sc);  // first key: exp(-huge)=0
          l = l * al + 1.f;
#pragma unroll
          for (int d = 0; d < 64; ++d) out[d] = out[d] * al + vr[d];
          mrun = sc;
        }
      }
    }
  }

  // stage normalized msg in vs, then coalesced bf16 store
  __syncthreads();
  if (act) {
    float inv = 1.f / l;
#pragma unroll
    for (int d = 0; d < 64; ++d) vs[r * 64 + d] = out[d] * inv;
  }
  __syncthreads();
  for (int i = tid; i < 197 * 64; i += 256) {
    int m = i >> 6, d = i & 63;
    msgbuf[(size_t)e * 37824 + m * 192 + h * 64 + d] = f2bf(vs[i]);
  }
}

// ---------------------------------------------------------------------------
// Phase B: per-dst aggregation.  grid (256 dst, 4 chunks).  agg = sum msgbuf; cnt.
// ---------------------------------------------------------------------------
__global__ __launch_bounds__(256) void aggregate_kernel(
    const unsigned short* __restrict__ msgbuf, const int* __restrict__ edge,
    unsigned short* __restrict__ agg, int* __restrict__ cntg) {
  const int b = blockIdx.x, chunk = blockIdx.y;
  __shared__ int list[1024];
  __shared__ int lc;
  const int tid = threadIdx.x;
  if (tid == 0) lc = 0;
  __syncthreads();
  for (int e = tid; e < 1024; e += 256)
    if (edge[1024 + e] == b) { int p = atomicAdd(&lc, 1); list[p] = e; }
  __syncthreads();
  const int cnt = lc;
  if (chunk == 0 && tid == 0) cntg[b] = cnt;
  const int end = (chunk + 1) * 9456;  // 37824 = 4*9456
  for (int i = chunk * 9456 + tid; i < end; i += 256) {
    float sum = 0.f;
    for (int j = 0; j < cnt; ++j) sum += bf2f(msgbuf[(size_t)list[j] * 37824 + i]);
    agg[(size_t)b * 37824 + i] = f2bf(sum);
  }
}

// ---------------------------------------------------------------------------
extern "C" void kernel_launch(void* const* d_in, const int* in_sizes, int n_in,
                              void* d_out, int out_size, void* d_ws, size_t ws_size,
                              hipStream_t stream) {
  const float* x      = (const float*)d_in[0];
  const int*   edge   = (const int*)d_in[1];
  const float* n1g    = (const float*)d_in[2];
  const float* n1b    = (const float*)d_in[3];
  const float* qkv_w  = (const float*)d_in[4];
  const float* proj_w = (const float*)d_in[5];
  const float* proj_b = (const float*)d_in[6];
  const float* n2g    = (const float*)d_in[7];
  const float* n2b    = (const float*)d_in[8];
  const float* fc1_w  = (const float*)d_in[9];
  const float* fc1_b  = (const float*)d_in[10];
  const float* fc2_w  = (const float*)d_in[11];
  const float* fc2_b  = (const float*)d_in[12];
  float* out = (float*)d_out;

  char* ws = (char*)d_ws;
  unsigned short* msgbuf = (unsigned short*)ws;                    // 77,463,552 B
  unsigned short* h1     = (unsigned short*)ws;                    // overlays msgbuf (disjoint lifetime)
  unsigned short* qkv    = (unsigned short*)(ws + 77463552);       // 58,097,664 B
  unsigned short* xn     = (unsigned short*)(ws + 135561216);      // 19,365,888 B (also x2n)
  unsigned short* agg    = (unsigned short*)(ws + 154927104);      // 19,365,888 B
  unsigned short* wqkv   = (unsigned short*)(ws + 174292992);      // 221,184 B
  unsigned short* wproj  = (unsigned short*)(ws + 174514176);      // 73,728 B
  unsigned short* wfc1   = (unsigned short*)(ws + 174587904);      // 294,912 B
  unsigned short* wfc2   = (unsigned short*)(ws + 174882816);      // 294,912 B
  int*            cntg   = (int*)           (ws + 175177728);      // 1,024 B

  dim3 blk(256);
  f2bf_kernel<<<dim3(432), blk, 0, stream>>>(qkv_w, wqkv, 110592);
  f2bf_kernel<<<dim3(144), blk, 0, stream>>>(proj_w, wproj, 36864);
  f2bf_kernel<<<dim3(576), blk, 0, stream>>>(fc1_w, wfc1, 147456);
  f2bf_kernel<<<dim3(576), blk, 0, stream>>>(fc2_w, wfc2, 147456);

  // 1) xn = bf16(LN1(x))
  ln_bf16_kernel<<<dim3(12608), blk, 0, stream>>>(x, n1g, n1b, xn);
  // 2) qkv = xn @ qkv_w^T (bf16)
  gemm_bf16<0, 1><<<dim3(394, 9), blk, 0, stream>>>(xn, wqkv, nullptr, nullptr, nullptr, qkv, 576);
  // 3) per-(edge,head) attention -> msgbuf
  attnA_kernel<<<dim3(1024, 3), blk, 0, stream>>>(qkv, edge, msgbuf);
  // 4) agg = sum_edges msg, cnt
  aggregate_kernel<<<dim3(256, 4), blk, 0, stream>>>(msgbuf, edge, agg, cntg);
  // 5) x2 = x + proj(agg)/max(cnt,1) + proj_b*(cnt>0)  -> d_out (fp32)
  gemm_bf16<1, 1><<<dim3(394, 3), blk, 0, stream>>>(agg, wproj, proj_b, x, cntg, out, 192);
  // 6) x2n = bf16(LN2(x2))
  ln_bf16_kernel<<<dim3(12608), blk, 0, stream>>>(out, n2g, n2b, xn);
  // 7) h1 = bf16(gelu(x2n @ fc1_w^T + fc1_b))
  gemm_bf16<2, 1><<<dim3(394, 12), blk, 0, stream>>>(xn, wfc1, fc1_b, nullptr, nullptr, h1, 768);
  // 8) out = x2 + h1 @ fc2_w^T + fc2_b  (in-place per-element)
  gemm_bf16<3, 4><<<dim3(394, 3), blk, 0, stream>>>(h1, wfc2, fc2_b, out, nullptr, out, 192);
}

// Round 3
// 544.081 us; speedup vs baseline: 7.4491x; 2.3210x over previous
//
#include <hip/hip_runtime.h>
#include <hip/hip_bf16.h>
#include <cstddef>

// Bn=256, N=197, C=192, H=3, hd=64, E=1024, hid=768, M = Bn*N = 50432 = 394*128
//
// ws layout (bytes), total ~175.2 MB:
//   [0,          77463552)  : msgbuf bf16 [1024][197][192]  -- later overlaid by h1 bf16 [50432][768]
//   [77463552,  135561216)  : qkv bf16 [50432][576]
//   [135561216, 154927104)  : xn bf16 [50432][192]   (reused as x2n after proj)
//   [154927104, 174292992)  : agg bf16 [50432][192]
//   [174292992, ...)        : bf16 weights; cnt int32[256] at 175177728

typedef __attribute__((ext_vector_type(8))) short bf8_t;
typedef __attribute__((ext_vector_type(4))) float f4_t;

__device__ __forceinline__ float bf2f(unsigned short u) {
  union { unsigned int i; float f; } x; x.i = ((unsigned int)u) << 16; return x.f;
}
__device__ __forceinline__ unsigned short f2bf(float f) {
  unsigned int u = __builtin_bit_cast(unsigned int, f);
  u = (u + 0x7FFFu + ((u >> 16) & 1u)) >> 16;
  return (unsigned short)u;
}

// ---------------------------------------------------------------------------
__global__ __launch_bounds__(256) void f2bf_kernel(const float* __restrict__ src,
                                                   unsigned short* __restrict__ dst, int n) {
  int i = blockIdx.x * 256 + threadIdx.x;
  if (i < n) dst[i] = f2bf(src[i]);
}

// ---------------------------------------------------------------------------
// LayerNorm(fp32 in) -> bf16 out.  One wave per row (C=192, 3 elems/lane).
// ---------------------------------------------------------------------------
__global__ __launch_bounds__(256) void ln_bf16_kernel(const float* __restrict__ X,
    const float* __restrict__ g, const float* __restrict__ b,
    unsigned short* __restrict__ Y) {
  int row = blockIdx.x * 4 + (threadIdx.x >> 6);
  int lane = threadIdx.x & 63;
  const float* xr = X + (size_t)row * 192;
  float v0 = xr[lane], v1 = xr[lane + 64], v2 = xr[lane + 128];
  float s = v0 + v1 + v2, ss = v0 * v0 + v1 * v1 + v2 * v2;
#pragma unroll
  for (int o = 32; o > 0; o >>= 1) { s += __shfl_xor(s, o, 64); ss += __shfl_xor(ss, o, 64); }
  float mean = s * (1.f / 192.f);
  float var = ss * (1.f / 192.f) - mean * mean;
  float r = rsqrtf(var + 1e-5f);
  unsigned short* yr = Y + (size_t)row * 192;
  yr[lane]       = f2bf((v0 - mean) * r * g[lane]       + b[lane]);
  yr[lane + 64]  = f2bf((v1 - mean) * r * g[lane + 64]  + b[lane + 64]);
  yr[lane + 128] = f2bf((v2 - mean) * r * g[lane + 128] + b[lane + 128]);
}

// ---------------------------------------------------------------------------
// bf16 MFMA GEMM: C = f( A @ W^T ), tile 128x64, 4 waves.
// MODE 0: qkv->bf16; 1: proj->f32 (/cnt,+bias,+xres); 2: fc1->bf16 gelu; 3: fc2->f32 (+bias,+xres)
// ---------------------------------------------------------------------------
template<int MODE, int NK>
__global__ __launch_bounds__(256) void gemm_bf16(
    const unsigned short* __restrict__ A, const unsigned short* __restrict__ W,
    const float* __restrict__ bias, const float* __restrict__ xres,
    const int* __restrict__ cntg, void* __restrict__ Cout, int ldc) {
  constexpr int LDA = 200;
  __shared__ unsigned short As[128 * LDA];
  __shared__ unsigned short Ws[64 * LDA];
  const int tid = threadIdx.x;
  const int m0 = blockIdx.x * 128, n0 = blockIdx.y * 64;
  const int wave = tid >> 6, lane = tid & 63;
  const int mfrag = lane & 15, quad = lane >> 4;
  const int K = NK * 192;

  f4_t acc[2][4];
#pragma unroll
  for (int i = 0; i < 2; ++i)
#pragma unroll
    for (int j = 0; j < 4; ++j) acc[i][j] = (f4_t){0.f, 0.f, 0.f, 0.f};

  for (int kc = 0; kc < NK; ++kc) {
    __syncthreads();
#pragma unroll
    for (int it = 0; it < 12; ++it) {
      int idx = it * 256 + tid;
      int r = idx / 24, c = idx % 24;
      *(float4*)(As + r * LDA + c * 8) =
          *(const float4*)(A + (size_t)(m0 + r) * K + kc * 192 + c * 8);
    }
#pragma unroll
    for (int it = 0; it < 6; ++it) {
      int idx = it * 256 + tid;
      int r = idx / 24, c = idx % 24;
      *(float4*)(Ws + r * LDA + c * 8) =
          *(const float4*)(W + (size_t)(n0 + r) * K + kc * 192 + c * 8);
    }
    __syncthreads();
#pragma unroll
    for (int ks = 0; ks < 6; ++ks) {
      bf8_t a0 = *(const bf8_t*)(As + (wave * 32 + mfrag) * LDA + ks * 32 + quad * 8);
      bf8_t a1 = *(const bf8_t*)(As + (wave * 32 + 16 + mfrag) * LDA + ks * 32 + quad * 8);
#pragma unroll
      for (int nt = 0; nt < 4; ++nt) {
        bf8_t bf = *(const bf8_t*)(Ws + (nt * 16 + mfrag) * LDA + ks * 32 + quad * 8);
        acc[0][nt] = __builtin_amdgcn_mfma_f32_16x16x32_bf16(a0, bf, acc[0][nt], 0, 0, 0);
        acc[1][nt] = __builtin_amdgcn_mfma_f32_16x16x32_bf16(a1, bf, acc[1][nt], 0, 0, 0);
      }
    }
  }

#pragma unroll
  for (int mt = 0; mt < 2; ++mt)
#pragma unroll
    for (int nt = 0; nt < 4; ++nt)
#pragma unroll
      for (int reg = 0; reg < 4; ++reg) {
        int row = m0 + wave * 32 + mt * 16 + quad * 4 + reg;
        int col = n0 + nt * 16 + mfrag;
        float v = acc[mt][nt][reg];
        if constexpr (MODE == 0) {
          ((unsigned short*)Cout)[(size_t)row * ldc + col] = f2bf(v);
        } else if constexpr (MODE == 1) {
          int c = cntg[row / 197];
          v = (c > 0) ? v / (float)c + bias[col] : 0.f;
          v += xres[(size_t)row * 192 + col];
          ((float*)Cout)[(size_t)row * ldc + col] = v;
        } else if constexpr (MODE == 2) {
          v += bias[col];
          v = 0.5f * v * (1.f + erff(v * 0.70710678118654752f));
          ((unsigned short*)Cout)[(size_t)row * ldc + col] = f2bf(v);
        } else {
          v += bias[col] + xres[(size_t)row * 192 + col];
          ((float*)Cout)[(size_t)row * ldc + col] = v;
        }
      }
}

// ---------------------------------------------------------------------------
// MFMA attention, one block per (edge e, head h).  q,v from dst; k from src.
// S = Q@K^T (13 m-strips x 13 n-tiles of 16x16x32), exact row softmax in regs,
// P -> per-wave LDS chunk (dbuf) -> A-frags -> PV vs V^T in LDS.
// Layouts: Ks[key][72], Vt[d][232], Ps chunk 16x40 — all <=2-way bank aliasing.
// ---------------------------------------------------------------------------
__global__ __launch_bounds__(256) void attnA_kernel(
    const unsigned short* __restrict__ qkv, const int* __restrict__ edge,
    unsigned short* __restrict__ msgbuf) {
  const int e = blockIdx.x, h = blockIdx.y;
  const int s = edge[e], b = edge[1024 + e];
  __shared__ unsigned short Ks[208 * 72];
  __shared__ unsigned short Vt[64 * 232];
  __shared__ unsigned short Ps[4][2][640];   // [wave][parity][16*40]
  const int tid = threadIdx.x;
  const int wave = tid >> 6, lane = tid & 63;
  const int mfrag = lane & 15, quad = lane >> 4;

  // stage K rows (src s), coalesced 16B
  for (int i = tid; i < 197 * 8; i += 256) {
    int m = i >> 3, c8 = i & 7;
    *(float4*)(Ks + m * 72 + c8 * 8) =
        *(const float4*)(qkv + (size_t)(s * 197 + m) * 576 + 192 + h * 64 + c8 * 8);
  }
  // Vt zero-pad keys 197..231 (disjoint from data cols -> no race)
  for (int i = tid; i < 64 * 35; i += 256) {
    int d = i / 35, kk = 197 + i % 35;
    Vt[d * 232 + kk] = 0;
  }
  // stage V^T (dst b)
  for (int i = tid; i < 197 * 8; i += 256) {
    int m = i >> 3, c8 = i & 7;
    float4 t = *(const float4*)(qkv + (size_t)(b * 197 + m) * 576 + 384 + h * 64 + c8 * 8);
    const unsigned short* u = (const unsigned short*)&t;
#pragma unroll
    for (int j = 0; j < 8; ++j) Vt[(c8 * 8 + j) * 232 + m] = u[j];
  }
  __syncthreads();

  for (int st = wave; st < 13; st += 4) {
    const int m0 = st * 16;
    const size_t qrow = (size_t)(b * 197 + min(m0 + mfrag, 196)) * 576 + h * 64;
    bf8_t a0 = *(const bf8_t*)(qkv + qrow + quad * 8);
    bf8_t a1 = *(const bf8_t*)(qkv + qrow + 32 + quad * 8);

    f4_t S[13];
#pragma unroll
    for (int nt = 0; nt < 13; ++nt) {
      bf8_t k0 = *(const bf8_t*)(Ks + (nt * 16 + mfrag) * 72 + quad * 8);
      bf8_t k1 = *(const bf8_t*)(Ks + (nt * 16 + mfrag) * 72 + 32 + quad * 8);
      f4_t z = (f4_t){0.f, 0.f, 0.f, 0.f};
      z = __builtin_amdgcn_mfma_f32_16x16x32_bf16(a0, k0, z, 0, 0, 0);
      S[nt] = __builtin_amdgcn_mfma_f32_16x16x32_bf16(a1, k1, z, 0, 0, 0);
    }

    // exact softmax over keys; lane holds S[q=quad*4+reg][key=nt*16+mfrag]
    float mx[4] = {-1e30f, -1e30f, -1e30f, -1e30f};
#pragma unroll
    for (int nt = 0; nt < 13; ++nt) {
      int key = nt * 16 + mfrag;
#pragma unroll
      for (int reg = 0; reg < 4; ++reg) {
        float v = (key < 197) ? S[nt][reg] * 0.125f : -1e30f;
        S[nt][reg] = v;
        mx[reg] = fmaxf(mx[reg], v);
      }
    }
#pragma unroll
    for (int off = 1; off < 16; off <<= 1)
#pragma unroll
      for (int reg = 0; reg < 4; ++reg) mx[reg] = fmaxf(mx[reg], __shfl_xor(mx[reg], off, 64));
    float sum[4] = {0.f, 0.f, 0.f, 0.f};
#pragma unroll
    for (int nt = 0; nt < 13; ++nt)
#pragma unroll
      for (int reg = 0; reg < 4; ++reg) {
        float p = __expf(S[nt][reg] - mx[reg]);
        S[nt][reg] = p;
        sum[reg] += p;
      }
#pragma unroll
    for (int off = 1; off < 16; off <<= 1)
#pragma unroll
      for (int reg = 0; reg < 4; ++reg) sum[reg] += __shfl_xor(sum[reg], off, 64);
    float inv[4];
#pragma unroll
    for (int reg = 0; reg < 4; ++reg) inv[reg] = 1.f / sum[reg];

    // PV: chunked P->LDS (wave-private, parity dbuf; in-order DS per wave)
    f4_t o[4];
#pragma unroll
    for (int dt = 0; dt < 4; ++dt) o[dt] = (f4_t){0.f, 0.f, 0.f, 0.f};
#pragma unroll
    for (int kt = 0; kt < 7; ++kt) {
      unsigned short* buf = Ps[wave][kt & 1];
#pragma unroll
      for (int half = 0; half < 2; ++half) {
        int nt = kt * 2 + half;
#pragma unroll
        for (int reg = 0; reg < 4; ++reg) {
          float p = (nt < 13) ? S[nt][reg] : 0.f;
          buf[(quad * 4 + reg) * 40 + half * 16 + mfrag] = f2bf(p);
        }
      }
      bf8_t pf = *(const bf8_t*)(buf + mfrag * 40 + quad * 8);
#pragma unroll
      for (int dt = 0; dt < 4; ++dt) {
        bf8_t vf = *(const bf8_t*)(Vt + (dt * 16 + mfrag) * 232 + kt * 32 + quad * 8);
        o[dt] = __builtin_amdgcn_mfma_f32_16x16x32_bf16(pf, vf, o[dt], 0, 0, 0);
      }
    }

    // msg store: lane holds o[dt][reg] = out[q=quad*4+reg][d=dt*16+mfrag]
#pragma unroll
    for (int dt = 0; dt < 4; ++dt)
#pragma unroll
      for (int reg = 0; reg < 4; ++reg) {
        int q = m0 + quad * 4 + reg;
        if (q < 197)
          msgbuf[(size_t)e * 37824 + q * 192 + h * 64 + dt * 16 + mfrag] =
              f2bf(o[dt][reg] * inv[reg]);
      }
  }
}

// ---------------------------------------------------------------------------
// Per-dst aggregation.  grid (256 dst, 4 chunks).  agg = sum msgbuf; cnt.
// ---------------------------------------------------------------------------
__global__ __launch_bounds__(256) void aggregate_kernel(
    const unsigned short* __restrict__ msgbuf, const int* __restrict__ edge,
    unsigned short* __restrict__ agg, int* __restrict__ cntg) {
  const int b = blockIdx.x, chunk = blockIdx.y;
  __shared__ int list[1024];
  __shared__ int lc;
  const int tid = threadIdx.x;
  if (tid == 0) lc = 0;
  __syncthreads();
  for (int e = tid; e < 1024; e += 256)
    if (edge[1024 + e] == b) { int p = atomicAdd(&lc, 1); list[p] = e; }
  __syncthreads();
  const int cnt = lc;
  if (chunk == 0 && tid == 0) cntg[b] = cnt;
  const int end = (chunk + 1) * 9456;  // 37824 = 4*9456
  for (int i = chunk * 9456 + tid; i < end; i += 256) {
    float sum = 0.f;
    for (int j = 0; j < cnt; ++j) sum += bf2f(msgbuf[(size_t)list[j] * 37824 + i]);
    agg[(size_t)b * 37824 + i] = f2bf(sum);
  }
}

// ---------------------------------------------------------------------------
extern "C" void kernel_launch(void* const* d_in, const int* in_sizes, int n_in,
                              void* d_out, int out_size, void* d_ws, size_t ws_size,
                              hipStream_t stream) {
  const float* x      = (const float*)d_in[0];
  const int*   edge   = (const int*)d_in[1];
  const float* n1g    = (const float*)d_in[2];
  const float* n1b    = (const float*)d_in[3];
  const float* qkv_w  = (const float*)d_in[4];
  const float* proj_w = (const float*)d_in[5];
  const float* proj_b = (const float*)d_in[6];
  const float* n2g    = (const float*)d_in[7];
  const float* n2b    = (const float*)d_in[8];
  const float* fc1_w  = (const float*)d_in[9];
  const float* fc1_b  = (const float*)d_in[10];
  const float* fc2_w  = (const float*)d_in[11];
  const float* fc2_b  = (const float*)d_in[12];
  float* out = (float*)d_out;

  char* ws = (char*)d_ws;
  unsigned short* msgbuf = (unsigned short*)ws;
  unsigned short* h1     = (unsigned short*)ws;                    // overlays msgbuf
  unsigned short* qkv    = (unsigned short*)(ws + 77463552);
  unsigned short* xn     = (unsigned short*)(ws + 135561216);
  unsigned short* agg    = (unsigned short*)(ws + 154927104);
  unsigned short* wqkv   = (unsigned short*)(ws + 174292992);
  unsigned short* wproj  = (unsigned short*)(ws + 174514176);
  unsigned short* wfc1   = (unsigned short*)(ws + 174587904);
  unsigned short* wfc2   = (unsigned short*)(ws + 174882816);
  int*            cntg   = (int*)           (ws + 175177728);

  dim3 blk(256);
  f2bf_kernel<<<dim3(432), blk, 0, stream>>>(qkv_w, wqkv, 110592);
  f2bf_kernel<<<dim3(144), blk, 0, stream>>>(proj_w, wproj, 36864);
  f2bf_kernel<<<dim3(576), blk, 0, stream>>>(fc1_w, wfc1, 147456);
  f2bf_kernel<<<dim3(576), blk, 0, stream>>>(fc2_w, wfc2, 147456);

  ln_bf16_kernel<<<dim3(12608), blk, 0, stream>>>(x, n1g, n1b, xn);
  gemm_bf16<0, 1><<<dim3(394, 9), blk, 0, stream>>>(xn, wqkv, nullptr, nullptr, nullptr, qkv, 576);
  attnA_kernel<<<dim3(1024, 3), blk, 0, stream>>>(qkv, edge, msgbuf);
  aggregate_kernel<<<dim3(256, 4), blk, 0, stream>>>(msgbuf, edge, agg, cntg);
  gemm_bf16<1, 1><<<dim3(394, 3), blk, 0, stream>>>(agg, wproj, proj_b, x, cntg, out, 192);
  ln_bf16_kernel<<<dim3(12608), blk, 0, stream>>>(out, n2g, n2b, xn);
  gemm_bf16<2, 1><<<dim3(394, 12), blk, 0, stream>>>(xn, wfc1, fc1_b, nullptr, nullptr, h1, 768);
  gemm_bf16<3, 4><<<dim3(394, 3), blk, 0, stream>>>(h1, wfc2, fc2_b, out, nullptr, out, 192);
}

// Round 4
// 508.962 us; speedup vs baseline: 7.9631x; 1.0690x over previous
//
#include <hip/hip_runtime.h>
#include <hip/hip_bf16.h>
#include <cstddef>

// Bn=256, N=197, C=192, H=3, hd=64, E=1024, hid=768, M = Bn*N = 50432 = 394*128
//
// ws layout (bytes):
//   [0,          77463552)   : msgbuf bf16 [1024][197][192]  -- later overlaid by h1 bf16 [50432][768]
//   [77463552,  116195328)   : qk  bf16 [50432][384]   (Q cols 0..191, K cols 192..383)
//   [116195328, 135561216)   : xn  bf16 [50432][192]   (reused as x2n after proj)
//   [135561216, 154927104)   : agg bf16 [50432][192]
//   [154927104, 174587904)   : vt  bf16 [256][3][64][200]  (V transposed, t contiguous; cols 197..199 garbage)
//   [174587904, 175472640)   : bf16 weights (qkv, proj, fc1, fc2)
//   [175472640, 175473664)   : cnt int32[256]

typedef __attribute__((ext_vector_type(8))) short bf8_t;
typedef __attribute__((ext_vector_type(4))) float f4_t;

__device__ __forceinline__ float bf2f(unsigned short u) {
  union { unsigned int i; float f; } x; x.i = ((unsigned int)u) << 16; return x.f;
}
__device__ __forceinline__ unsigned short f2bf(float f) {
  unsigned int u = __builtin_bit_cast(unsigned int, f);
  u = (u + 0x7FFFu + ((u >> 16) & 1u)) >> 16;
  return (unsigned short)u;
}

// ---------------------------------------------------------------------------
__global__ __launch_bounds__(256) void f2bf_kernel(const float* __restrict__ src,
                                                   unsigned short* __restrict__ dst, int n) {
  int i = blockIdx.x * 256 + threadIdx.x;
  if (i < n) dst[i] = f2bf(src[i]);
}

// ---------------------------------------------------------------------------
// LayerNorm(fp32 in) -> bf16 out.  One wave per row (C=192, 3 elems/lane).
// ---------------------------------------------------------------------------
__global__ __launch_bounds__(256) void ln_bf16_kernel(const float* __restrict__ X,
    const float* __restrict__ g, const float* __restrict__ b,
    unsigned short* __restrict__ Y) {
  int row = blockIdx.x * 4 + (threadIdx.x >> 6);
  int lane = threadIdx.x & 63;
  const float* xr = X + (size_t)row * 192;
  float v0 = xr[lane], v1 = xr[lane + 64], v2 = xr[lane + 128];
  float s = v0 + v1 + v2, ss = v0 * v0 + v1 * v1 + v2 * v2;
#pragma unroll
  for (int o = 32; o > 0; o >>= 1) { s += __shfl_xor(s, o, 64); ss += __shfl_xor(ss, o, 64); }
  float mean = s * (1.f / 192.f);
  float var = ss * (1.f / 192.f) - mean * mean;
  float r = rsqrtf(var + 1e-5f);
  unsigned short* yr = Y + (size_t)row * 192;
  yr[lane]       = f2bf((v0 - mean) * r * g[lane]       + b[lane]);
  yr[lane + 64]  = f2bf((v1 - mean) * r * g[lane + 64]  + b[lane + 64]);
  yr[lane + 128] = f2bf((v2 - mean) * r * g[lane + 128] + b[lane + 128]);
}

// ---------------------------------------------------------------------------
// bf16 MFMA GEMM: C = f( A @ W^T ), tile 128x64, 4 waves.
// MODE 0: qkv -> qk bf16 (cols<384) + vt bf16 transposed (cols>=384)
// MODE 1: proj -> f32 (/cnt, +bias, +xres)
// MODE 2: fc1 -> bf16 gelu(+bias)
// MODE 3: fc2 -> f32 (+bias, +xres; in-place safe per-element)
// ---------------------------------------------------------------------------
template<int MODE, int NK>
__global__ __launch_bounds__(256) void gemm_bf16(
    const unsigned short* __restrict__ A, const unsigned short* __restrict__ W,
    const float* __restrict__ bias, const float* __restrict__ xres,
    const int* __restrict__ cntg, void* __restrict__ Cout,
    unsigned short* __restrict__ Cvt, int ldc) {
  constexpr int LDA = 200;
  __shared__ unsigned short As[128 * LDA];
  __shared__ unsigned short Ws[64 * LDA];
  const int tid = threadIdx.x;
  const int m0 = blockIdx.x * 128, n0 = blockIdx.y * 64;
  const int wave = tid >> 6, lane = tid & 63;
  const int mfrag = lane & 15, quad = lane >> 4;
  const int K = NK * 192;

  f4_t acc[2][4];
#pragma unroll
  for (int i = 0; i < 2; ++i)
#pragma unroll
    for (int j = 0; j < 4; ++j) acc[i][j] = (f4_t){0.f, 0.f, 0.f, 0.f};

  for (int kc = 0; kc < NK; ++kc) {
    __syncthreads();
#pragma unroll
    for (int it = 0; it < 12; ++it) {
      int idx = it * 256 + tid;
      int r = idx / 24, c = idx % 24;
      *(float4*)(As + r * LDA + c * 8) =
          *(const float4*)(A + (size_t)(m0 + r) * K + kc * 192 + c * 8);
    }
#pragma unroll
    for (int it = 0; it < 6; ++it) {
      int idx = it * 256 + tid;
      int r = idx / 24, c = idx % 24;
      *(float4*)(Ws + r * LDA + c * 8) =
          *(const float4*)(W + (size_t)(n0 + r) * K + kc * 192 + c * 8);
    }
    __syncthreads();
#pragma unroll
    for (int ks = 0; ks < 6; ++ks) {
      bf8_t a0 = *(const bf8_t*)(As + (wave * 32 + mfrag) * LDA + ks * 32 + quad * 8);
      bf8_t a1 = *(const bf8_t*)(As + (wave * 32 + 16 + mfrag) * LDA + ks * 32 + quad * 8);
#pragma unroll
      for (int nt = 0; nt < 4; ++nt) {
        bf8_t bf = *(const bf8_t*)(Ws + (nt * 16 + mfrag) * LDA + ks * 32 + quad * 8);
        acc[0][nt] = __builtin_amdgcn_mfma_f32_16x16x32_bf16(a0, bf, acc[0][nt], 0, 0, 0);
        acc[1][nt] = __builtin_amdgcn_mfma_f32_16x16x32_bf16(a1, bf, acc[1][nt], 0, 0, 0);
      }
    }
  }

#pragma unroll
  for (int mt = 0; mt < 2; ++mt)
#pragma unroll
    for (int nt = 0; nt < 4; ++nt)
#pragma unroll
      for (int reg = 0; reg < 4; ++reg) {
        int row = m0 + wave * 32 + mt * 16 + quad * 4 + reg;
        int col = n0 + nt * 16 + mfrag;
        float v = acc[mt][nt][reg];
        if constexpr (MODE == 0) {
          if (col < 384) {
            ((unsigned short*)Cout)[(size_t)row * 384 + col] = f2bf(v);
          } else {
            int cc = col - 384, hh = cc >> 6, dd = cc & 63;
            int bb = row / 197, tt = row - bb * 197;
            Cvt[((size_t)(bb * 3 + hh) * 64 + dd) * 200 + tt] = f2bf(v);
          }
        } else if constexpr (MODE == 1) {
          int c = cntg[row / 197];
          v = (c > 0) ? v / (float)c + bias[col] : 0.f;
          v += xres[(size_t)row * 192 + col];
          ((float*)Cout)[(size_t)row * ldc + col] = v;
        } else if constexpr (MODE == 2) {
          v += bias[col];
          v = 0.5f * v * (1.f + erff(v * 0.70710678118654752f));
          ((unsigned short*)Cout)[(size_t)row * ldc + col] = f2bf(v);
        } else {
          v += bias[col] + xres[(size_t)row * 192 + col];
          ((float*)Cout)[(size_t)row * ldc + col] = v;
        }
      }
}

// ---------------------------------------------------------------------------
// MFMA attention, one block per (edge e, head h).  q,v from dst; k from src.
// K staged row-major from qk; V^T staged row-major from pre-transposed vt
// (conflict-free b128 writes).  S = Q@K^T, exact softmax in regs, P->LDS->PV.
// ---------------------------------------------------------------------------
__global__ __launch_bounds__(256) void attnA_kernel(
    const unsigned short* __restrict__ qk, const unsigned short* __restrict__ vtg,
    const int* __restrict__ edge, unsigned short* __restrict__ msgbuf) {
  const int e = blockIdx.x, h = blockIdx.y;
  const int s = edge[e], b = edge[1024 + e];
  __shared__ unsigned short Ks[208 * 72];
  __shared__ unsigned short Vt[64 * 232];
  __shared__ unsigned short Ps[4][2][640];   // [wave][parity][16*40]
  const int tid = threadIdx.x;
  const int wave = tid >> 6, lane = tid & 63;
  const int mfrag = lane & 15, quad = lane >> 4;

  // stage K rows (src s), coalesced 16B, conflict-free
  for (int i = tid; i < 197 * 8; i += 256) {
    int m = i >> 3, c8 = i & 7;
    *(float4*)(Ks + m * 72 + c8 * 8) =
        *(const float4*)(qk + (size_t)(s * 197 + m) * 384 + 192 + h * 64 + c8 * 8);
  }
  // stage V^T rows (dst b) from pre-transposed global, b128 conflict-free
  for (int i = tid; i < 64 * 25; i += 256) {
    int d = i / 25, c8 = i - d * 25;
    *(float4*)(Vt + d * 232 + c8 * 8) =
        *(const float4*)(vtg + ((size_t)(b * 3 + h) * 64 + d) * 200 + c8 * 8);
  }
  __syncthreads();
  // zero pad keys 197..231 (197..199 overwrite staged garbage)
  for (int i = tid; i < 64 * 35; i += 256) {
    int d = i / 35, kk = 197 + (i - d * 35);
    Vt[d * 232 + kk] = 0;
  }
  __syncthreads();

  for (int st = wave; st < 13; st += 4) {
    const int m0 = st * 16;
    const size_t qrow = (size_t)(b * 197 + min(m0 + mfrag, 196)) * 384 + h * 64;
    bf8_t a0 = *(const bf8_t*)(qk + qrow + quad * 8);
    bf8_t a1 = *(const bf8_t*)(qk + qrow + 32 + quad * 8);

    f4_t S[13];
#pragma unroll
    for (int nt = 0; nt < 13; ++nt) {
      bf8_t k0 = *(const bf8_t*)(Ks + (nt * 16 + mfrag) * 72 + quad * 8);
      bf8_t k1 = *(const bf8_t*)(Ks + (nt * 16 + mfrag) * 72 + 32 + quad * 8);
      f4_t z = (f4_t){0.f, 0.f, 0.f, 0.f};
      z = __builtin_amdgcn_mfma_f32_16x16x32_bf16(a0, k0, z, 0, 0, 0);
      S[nt] = __builtin_amdgcn_mfma_f32_16x16x32_bf16(a1, k1, z, 0, 0, 0);
    }

    // exact softmax over keys; lane holds S[q=quad*4+reg][key=nt*16+mfrag]
    float mx[4] = {-1e30f, -1e30f, -1e30f, -1e30f};
#pragma unroll
    for (int nt = 0; nt < 13; ++nt) {
      int key = nt * 16 + mfrag;
#pragma unroll
      for (int reg = 0; reg < 4; ++reg) {
        float v = (key < 197) ? S[nt][reg] * 0.125f : -1e30f;
        S[nt][reg] = v;
        mx[reg] = fmaxf(mx[reg], v);
      }
    }
#pragma unroll
    for (int off = 1; off < 16; off <<= 1)
#pragma unroll
      for (int reg = 0; reg < 4; ++reg) mx[reg] = fmaxf(mx[reg], __shfl_xor(mx[reg], off, 64));
    float sum[4] = {0.f, 0.f, 0.f, 0.f};
#pragma unroll
    for (int nt = 0; nt < 13; ++nt)
#pragma unroll
      for (int reg = 0; reg < 4; ++reg) {
        float p = __expf(S[nt][reg] - mx[reg]);
        S[nt][reg] = p;
        sum[reg] += p;
      }
#pragma unroll
    for (int off = 1; off < 16; off <<= 1)
#pragma unroll
      for (int reg = 0; reg < 4; ++reg) sum[reg] += __shfl_xor(sum[reg], off, 64);
    float inv[4];
#pragma unroll
    for (int reg = 0; reg < 4; ++reg) inv[reg] = 1.f / sum[reg];

    // PV: chunked P->LDS (wave-private, parity dbuf; in-order DS per wave)
    f4_t o[4];
#pragma unroll
    for (int dt = 0; dt < 4; ++dt) o[dt] = (f4_t){0.f, 0.f, 0.f, 0.f};
#pragma unroll
    for (int kt = 0; kt < 7; ++kt) {
      unsigned short* buf = Ps[wave][kt & 1];
#pragma unroll
      for (int half = 0; half < 2; ++half) {
        int nt = kt * 2 + half;
#pragma unroll
        for (int reg = 0; reg < 4; ++reg) {
          float p = (nt < 13) ? S[nt][reg] : 0.f;
          buf[(quad * 4 + reg) * 40 + half * 16 + mfrag] = f2bf(p);
        }
      }
      bf8_t pf = *(const bf8_t*)(buf + mfrag * 40 + quad * 8);
#pragma unroll
      for (int dt = 0; dt < 4; ++dt) {
        bf8_t vf = *(const bf8_t*)(Vt + (dt * 16 + mfrag) * 232 + kt * 32 + quad * 8);
        o[dt] = __builtin_amdgcn_mfma_f32_16x16x32_bf16(pf, vf, o[dt], 0, 0, 0);
      }
    }

    // msg store: lane holds o[dt][reg] = out[q=quad*4+reg][d=dt*16+mfrag]
#pragma unroll
    for (int dt = 0; dt < 4; ++dt)
#pragma unroll
      for (int reg = 0; reg < 4; ++reg) {
        int q = m0 + quad * 4 + reg;
        if (q < 197)
          msgbuf[(size_t)e * 37824 + q * 192 + h * 64 + dt * 16 + mfrag] =
              f2bf(o[dt][reg] * inv[reg]);
      }
  }
}

// ---------------------------------------------------------------------------
// Per-dst aggregation, bf16x8 vectorized.  grid (256 dst, 4 chunks).
// ---------------------------------------------------------------------------
__global__ __launch_bounds__(256) void aggregate_kernel(
    const unsigned short* __restrict__ msgbuf, const int* __restrict__ edge,
    unsigned short* __restrict__ agg, int* __restrict__ cntg) {
  const int b = blockIdx.x, chunk = blockIdx.y;
  __shared__ int list[1024];
  __shared__ int lc;
  const int tid = threadIdx.x;
  if (tid == 0) lc = 0;
  __syncthreads();
  for (int e = tid; e < 1024; e += 256)
    if (edge[1024 + e] == b) { int p = atomicAdd(&lc, 1); list[p] = e; }
  __syncthreads();
  const int cnt = lc;
  if (chunk == 0 && tid == 0) cntg[b] = cnt;
  const int base = chunk * 9456;  // 37824 = 4*9456, 9456 = 1182*8
  for (int i8 = tid; i8 < 1182; i8 += 256) {
    int i = base + i8 * 8;
    float sum[8];
#pragma unroll
    for (int kk = 0; kk < 8; ++kk) sum[kk] = 0.f;
    for (int j = 0; j < cnt; ++j) {
      float4 t = *(const float4*)(msgbuf + (size_t)list[j] * 37824 + i);
      const unsigned short* u = (const unsigned short*)&t;
#pragma unroll
      for (int kk = 0; kk < 8; ++kk) sum[kk] += bf2f(u[kk]);
    }
    unsigned short o[8];
#pragma unroll
    for (int kk = 0; kk < 8; ++kk) o[kk] = f2bf(sum[kk]);
    *(float4*)(agg + (size_t)b * 37824 + i) = *(const float4*)o;
  }
}

// ---------------------------------------------------------------------------
extern "C" void kernel_launch(void* const* d_in, const int* in_sizes, int n_in,
                              void* d_out, int out_size, void* d_ws, size_t ws_size,
                              hipStream_t stream) {
  const float* x      = (const float*)d_in[0];
  const int*   edge   = (const int*)d_in[1];
  const float* n1g    = (const float*)d_in[2];
  const float* n1b    = (const float*)d_in[3];
  const float* qkv_w  = (const float*)d_in[4];
  const float* proj_w = (const float*)d_in[5];
  const float* proj_b = (const float*)d_in[6];
  const float* n2g    = (const float*)d_in[7];
  const float* n2b    = (const float*)d_in[8];
  const float* fc1_w  = (const float*)d_in[9];
  const float* fc1_b  = (const float*)d_in[10];
  const float* fc2_w  = (const float*)d_in[11];
  const float* fc2_b  = (const float*)d_in[12];
  float* out = (float*)d_out;

  char* ws = (char*)d_ws;
  unsigned short* msgbuf = (unsigned short*)ws;
  unsigned short* h1     = (unsigned short*)ws;                    // overlays msgbuf
  unsigned short* qk     = (unsigned short*)(ws + 77463552);
  unsigned short* xn     = (unsigned short*)(ws + 116195328);
  unsigned short* agg    = (unsigned short*)(ws + 135561216);
  unsigned short* vtg    = (unsigned short*)(ws + 154927104);
  unsigned short* wqkv   = (unsigned short*)(ws + 174587904);
  unsigned short* wproj  = (unsigned short*)(ws + 174809088);
  unsigned short* wfc1   = (unsigned short*)(ws + 174882816);
  unsigned short* wfc2   = (unsigned short*)(ws + 175177728);
  int*            cntg   = (int*)           (ws + 175472640);

  dim3 blk(256);
  f2bf_kernel<<<dim3(432), blk, 0, stream>>>(qkv_w, wqkv, 110592);
  f2bf_kernel<<<dim3(144), blk, 0, stream>>>(proj_w, wproj, 36864);
  f2bf_kernel<<<dim3(576), blk, 0, stream>>>(fc1_w, wfc1, 147456);
  f2bf_kernel<<<dim3(576), blk, 0, stream>>>(fc2_w, wfc2, 147456);

  ln_bf16_kernel<<<dim3(12608), blk, 0, stream>>>(x, n1g, n1b, xn);
  gemm_bf16<0, 1><<<dim3(394, 9), blk, 0, stream>>>(xn, wqkv, nullptr, nullptr, nullptr, qk, vtg, 384);
  attnA_kernel<<<dim3(1024, 3), blk, 0, stream>>>(qk, vtg, edge, msgbuf);
  aggregate_kernel<<<dim3(256, 4), blk, 0, stream>>>(msgbuf, edge, agg, cntg);
  gemm_bf16<1, 1><<<dim3(394, 3), blk, 0, stream>>>(agg, wproj, proj_b, x, cntg, out, nullptr, 192);
  ln_bf16_kernel<<<dim3(12608), blk, 0, stream>>>(out, n2g, n2b, xn);
  gemm_bf16<2, 1><<<dim3(394, 12), blk, 0, stream>>>(xn, wfc1, fc1_b, nullptr, nullptr, h1, nullptr, 768);
  gemm_bf16<3, 4><<<dim3(394, 3), blk, 0, stream>>>(h1, wfc2, fc2_b, out, nullptr, out, nullptr, 192);
}